// Round 11
// baseline (123.745 us; speedup 1.0000x reference)
//
#include <hip/hip_runtime.h>
#include <hip/hip_bf16.h>

constexpr int NB   = 2;
constexpr int CIN  = 128;
constexpr int TT   = 8;
constexpr int HH   = 56;
constexpr int WW   = 56;
constexpr int S    = TT * HH * WW;      // 25088
constexpr int DK   = 16;
constexpr int DV   = 128;
constexpr int TAPS = 147;               // 3*7*7
constexpr int NOUT = DK + DV;           // 144
// bf16 channel-first padded v: [b][c:128][t:10][h:62][w:64]
constexpr int VPT = 10, VPH = 62, VPWA = 64;
constexpr int PLANE_A = VPT * VPH * VPWA;     // 39680 bf16 per channel
constexpr int BSTR = 74;   // Band w-row stride in shorts = 37 dwords (odd -> conflict-free)
constexpr float EPSf = 1e-6f;

typedef short bf16x8 __attribute__((ext_vector_type(8)));
typedef float f32x4  __attribute__((ext_vector_type(4)));

static __device__ __forceinline__ short f2bf(float f) {
    __hip_bfloat16 h = __float2bfloat16(f);   // RNE
    short s;
    __builtin_memcpy(&s, &h, 2);
    return s;
}

// ---------------------------------------------------------------------------
// k_twp: pack W_proj into MFMA A-fragment order (bf16).  (unchanged)
// ---------------------------------------------------------------------------
__global__ __launch_bounds__(256) void k_twp(
    const float* __restrict__ Wp, short* __restrict__ Wpfrag)
{
    int gid = blockIdx.x * 256 + threadIdx.x;   // < 9*4*64 = 2304
    if (gid >= 9 * 4 * 64) return;
    int lane = gid & 63;
    int kb   = (gid >> 6) & 3;
    int mt   = gid >> 8;
    int n = mt * 16 + (lane & 15);
    int c0 = kb * 32 + (lane >> 4) * 8;
#pragma unroll
    for (int j = 0; j < 8; ++j)
        Wpfrag[(size_t)gid * 8 + j] = f2bf(Wp[n * CIN + c0 + j]);
}

// ---------------------------------------------------------------------------
// k_proj (MFMA, swapped roles): unchanged from R10.
// ---------------------------------------------------------------------------
__global__ __launch_bounds__(256) void k_proj(
    const float* __restrict__ x, const short* __restrict__ Wpfrag,
    float* __restrict__ qn, short* __restrict__ vclb)
{
    int tid  = threadIdx.x;
    int lane = tid & 63;
    int wv   = tid >> 6;
    int bid  = blockIdx.x;                 // < NB * S/128 = 392
    int b    = bid / (S / 128);
    int pbas = (bid - b * (S / 128)) * 128 + wv * 32;

    const float* xb = x + (size_t)b * CIN * S;
    int col = lane & 15;
    int g   = lane >> 4;

    bf16x8 bx[2][4];
#pragma unroll
    for (int n2 = 0; n2 < 2; ++n2) {
        int p = pbas + n2 * 16 + col;
#pragma unroll
        for (int kb = 0; kb < 4; ++kb) {
            const float* xs = xb + (size_t)(kb * 32 + g * 8) * S + p;
#pragma unroll
            for (int j = 0; j < 8; ++j)
                bx[n2][kb][j] = f2bf(xs[(size_t)j * S]);
        }
    }

    f32x4 acc[9][2];
#pragma unroll
    for (int mt = 0; mt < 9; ++mt) {
        acc[mt][0] = {0.f, 0.f, 0.f, 0.f};
        acc[mt][1] = {0.f, 0.f, 0.f, 0.f};
    }

    const bf16x8* wf = reinterpret_cast<const bf16x8*>(Wpfrag);
#pragma unroll
    for (int mt = 0; mt < 9; ++mt) {
#pragma unroll
        for (int kb = 0; kb < 4; ++kb) {
            bf16x8 aw = wf[(mt * 4 + kb) * 64 + lane];
            acc[mt][0] = __builtin_amdgcn_mfma_f32_16x16x32_bf16(
                aw, bx[0][kb], acc[mt][0], 0, 0, 0);
            acc[mt][1] = __builtin_amdgcn_mfma_f32_16x16x32_bf16(
                aw, bx[1][kb], acc[mt][1], 0, 0, 0);
        }
    }

#pragma unroll
    for (int n2 = 0; n2 < 2; ++n2) {
        float ssq = 0.f, ssv = 0.f;
#pragma unroll
        for (int r = 0; r < 4; ++r) ssq += acc[0][n2][r] * acc[0][n2][r];
#pragma unroll
        for (int mt = 1; mt < 9; ++mt)
#pragma unroll
            for (int r = 0; r < 4; ++r) ssv += acc[mt][n2][r] * acc[mt][n2][r];
        ssq += __shfl_xor(ssq, 16, 64);
        ssq += __shfl_xor(ssq, 32, 64);
        ssv += __shfl_xor(ssv, 16, 64);
        ssv += __shfl_xor(ssv, 32, 64);
        float qsc = 1.0f / sqrtf(ssq + EPSf);
        float vsc = 1.0f / sqrtf(ssv + EPSf);

        int p = pbas + n2 * 16 + col;
#pragma unroll
        for (int r = 0; r < 4; ++r)
            qn[((size_t)b * DK + (4 * g + r)) * S + p] = acc[0][n2][r] * qsc;

        int t  = p / (HH * WW);
        int hw = p - t * (HH * WW);
        int h  = hw / WW;
        int w  = hw - h * WW;
        size_t pp = (size_t)(t + 1) * (VPH * VPWA) + (size_t)(h + 3) * VPWA + (w + 3);
        short* vb = vclb + (size_t)b * 128 * PLANE_A + pp;
#pragma unroll
        for (int mt = 1; mt < 9; ++mt)
#pragma unroll
            for (int r = 0; r < 4; ++r) {
                int c = (mt - 1) * 16 + 4 * g + r;
                vb[(size_t)c * PLANE_A] = f2bf(acc[mt][n2][r] * vsc);
            }
    }
}

// ---------------------------------------------------------------------------
// k_out (banded MFMA v2): per (b,t,h) row.
//   - BSTR=74 (37 dwords, odd) -> conflict-free B-frag ds_read_b128
//   - band sparsity: only (n,kb) in {(0,0),(1,0),(1,1),(2,1),(3,1)} nonzero
//     -> 5 ds_reads + 10 MFMA per row (was 8 + 16)
//   - A-frags prefetched one row ahead (global loads hidden under MFMA+barrier)
// ---------------------------------------------------------------------------
__global__ __launch_bounds__(256, 2) void k_out(
    const short* __restrict__ vclb, const float* __restrict__ qn,
    const float* __restrict__ wh2, float* __restrict__ out)
{
    __shared__ short weff_b[56 * 168];            // [w][row21][8] bf16, 18816 B
    __shared__ char  upool[2 * 64 * BSTR * 2];    // q_s (phase1) then Band dbuf, 18944 B

    int tid  = threadIdx.x;
    int lane = tid & 63;
    int wv   = tid >> 6;
    // XCD-chunked swizzle: 896 = 8 * 112
    int bid = blockIdx.x;
    int nid = (bid & 7) * 112 + (bid >> 3);
    int b   = nid / 448;
    int rem = nid - b * 448;
    int t   = rem / 56, h = rem - t * 56;
    int pbase = t * (HH * WW) + h * WW;

    int col = lane & 15, g = lane >> 4;
    int cbase = wv * 32;

    // ---- A-frag prefetch for row 0 (issued before phase 1; no LDS dep)
    const short* vb  = vclb + (size_t)b * 128 * PLANE_A;
    const short* ap0 = vb + (size_t)(cbase + col) * PLANE_A + g * 8;
    const short* ap1 = vb + (size_t)(cbase + 16 + col) * PLANE_A + g * 8;
    size_t o0 = (size_t)(t + 0) * (VPH * VPWA) + (size_t)(h + 0) * VPWA;
    bf16x8 avc[2][2], avn[2][2];
    avc[0][0] = *reinterpret_cast<const bf16x8*>(ap0 + o0);
    avc[0][1] = *reinterpret_cast<const bf16x8*>(ap0 + o0 + 32);
    avc[1][0] = *reinterpret_cast<const bf16x8*>(ap1 + o0);
    avc[1][1] = *reinterpret_cast<const bf16x8*>(ap1 + o0 + 32);

    // ---- Phase 1a: stage q row
    float* q_s = reinterpret_cast<float*>(upool);
    for (int i = tid; i < DK * WW; i += 256) {
        int k = i / 56, w = i - k * 56;
        q_s[i] = qn[((size_t)b * DK + k) * S + pbase + w];
    }
    __syncthreads();

    // ---- Phase 1b: weff[w][row][d] (bf16)
    if (tid < 224) {
        int w = tid % 56, q4 = tid / 56;
        float qr[DK];
#pragma unroll
        for (int k = 0; k < DK; ++k) qr[k] = q_s[k * 56 + w];
#pragma unroll 1
        for (int tap = q4; tap < TAPS; tap += 4) {
            float a = 0.f;
#pragma unroll
            for (int k = 0; k < DK; ++k)
                a = fmaf(qr[k], wh2[k * TAPS + tap], a);
            int row = tap / 7, d = tap - row * 7;
            weff_b[w * 168 + row * 8 + d] = f2bf(a);
        }
    }
    __syncthreads();

    // ---- zero Band double-buffer (q_s is dead now)
    short* band = reinterpret_cast<short*>(upool);
    {
        int* bi = reinterpret_cast<int*>(band);
        for (int i = tid; i < 2 * 64 * BSTR / 2; i += 256) bi[i] = 0;
    }
    __syncthreads();

    // build slots (same every row)
    int e1 = tid;
    int w1 = e1 / 7, d1 = e1 - w1 * 7;
    int e2 = tid + 256;
    int w2 = e2 / 7, d2 = e2 - w2 * 7;
    bool has2 = (e2 < 392);

    // build row 0 into buf 0
    band[w1 * BSTR + w1 + d1] = weff_b[w1 * 168 + d1];
    if (has2) band[w2 * BSTR + w2 + d2] = weff_b[w2 * 168 + d2];
    __syncthreads();

    f32x4 acc[2][4];
#pragma unroll
    for (int m2 = 0; m2 < 2; ++m2)
#pragma unroll
        for (int n = 0; n < 4; ++n) acc[m2][n] = {0.f, 0.f, 0.f, 0.f};

#pragma unroll 1
    for (int r = 0; r < 21; ++r) {
        // prefetch A-frags for row r+1 (consumed after the barrier)
        if (r < 20) {
            int r1 = r + 1;
            int dz = r1 / 7, dy = r1 - dz * 7;
            size_t o = (size_t)(t + dz) * (VPH * VPWA) + (size_t)(h + dy) * VPWA;
            avn[0][0] = *reinterpret_cast<const bf16x8*>(ap0 + o);
            avn[0][1] = *reinterpret_cast<const bf16x8*>(ap0 + o + 32);
            avn[1][0] = *reinterpret_cast<const bf16x8*>(ap1 + o);
            avn[1][1] = *reinterpret_cast<const bf16x8*>(ap1 + o + 32);
        }

        const short* cur = band + (r & 1) * (64 * BSTR);
        // sparse B-frags: (n,kb) in {(0,0),(1,0),(1,1),(2,1),(3,1)}
        bf16x8 b00 = *reinterpret_cast<const bf16x8*>(cur + (0 * 16 + col) * BSTR + g * 8);
        bf16x8 b10 = *reinterpret_cast<const bf16x8*>(cur + (1 * 16 + col) * BSTR + g * 8);
        bf16x8 b11 = *reinterpret_cast<const bf16x8*>(cur + (1 * 16 + col) * BSTR + 32 + g * 8);
        bf16x8 b21 = *reinterpret_cast<const bf16x8*>(cur + (2 * 16 + col) * BSTR + 32 + g * 8);
        bf16x8 b31 = *reinterpret_cast<const bf16x8*>(cur + (3 * 16 + col) * BSTR + 32 + g * 8);

#pragma unroll
        for (int m2 = 0; m2 < 2; ++m2) {
            acc[m2][0] = __builtin_amdgcn_mfma_f32_16x16x32_bf16(
                avc[m2][0], b00, acc[m2][0], 0, 0, 0);
            acc[m2][1] = __builtin_amdgcn_mfma_f32_16x16x32_bf16(
                avc[m2][0], b10, acc[m2][1], 0, 0, 0);
            acc[m2][1] = __builtin_amdgcn_mfma_f32_16x16x32_bf16(
                avc[m2][1], b11, acc[m2][1], 0, 0, 0);
            acc[m2][2] = __builtin_amdgcn_mfma_f32_16x16x32_bf16(
                avc[m2][1], b21, acc[m2][2], 0, 0, 0);
            acc[m2][3] = __builtin_amdgcn_mfma_f32_16x16x32_bf16(
                avc[m2][1], b31, acc[m2][3], 0, 0, 0);
        }

        // build band row r+1 into the other buffer
        if (r < 20) {
            short* nxt = band + ((r + 1) & 1) * (64 * BSTR);
            int ro = (r + 1) * 8;
            nxt[w1 * BSTR + w1 + d1] = weff_b[w1 * 168 + ro + d1];
            if (has2) nxt[w2 * BSTR + w2 + d2] = weff_b[w2 * 168 + ro + d2];
        }
        __syncthreads();

#pragma unroll
        for (int m2 = 0; m2 < 2; ++m2) {
            avc[m2][0] = avn[m2][0];
            avc[m2][1] = avn[m2][1];
        }
    }

    // ---- epilogue: D[m=c][n=w], c = cbase + m2*16 + 4g + rr, w = n*16 + col
#pragma unroll
    for (int m2 = 0; m2 < 2; ++m2) {
#pragma unroll
        for (int n = 0; n < 4; ++n) {
            int w = n * 16 + col;
            if (w < 56) {
                size_t ob = ((size_t)b * DV + cbase + m2 * 16 + 4 * g) * S + pbase + w;
#pragma unroll
                for (int rr = 0; rr < 4; ++rr)
                    out[ob + (size_t)rr * S] = acc[m2][n][rr];
            }
        }
    }
}

// ---------------------------------------------------------------------------
extern "C" void kernel_launch(void* const* d_in, const int* in_sizes, int n_in,
                              void* d_out, int out_size, void* d_ws, size_t ws_size,
                              hipStream_t stream)
{
    const float* x   = (const float*)d_in[0];   // (2,128,8,56,56)
    const float* Wp  = (const float*)d_in[1];   // (144,128)
    const float* wh2 = (const float*)d_in[2];   // (16,1,3,7,7) -> [k][147]
    float* out = (float*)d_out;                 // (2,128,8,56,56)

    float* ws     = (float*)d_ws;
    short* Wpfrag = (short*)ws;                        // 18,432 shorts
    float* qn     = ws + 9216;                         // NB*DK*S fp32
    short* vclb   = (short*)(qn + (size_t)NB * DK * S);// NB*128*PLANE_A bf16

    size_t vclb_bytes = (size_t)NB * 128 * PLANE_A * sizeof(short);  // 20.3 MB

    k_twp <<<dim3(9), dim3(256), 0, stream>>>(Wp, Wpfrag);
    hipMemsetAsync(vclb, 0, vclb_bytes, stream);
    k_proj<<<dim3(NB * S / 128), dim3(256), 0, stream>>>(x, Wpfrag, qn, vclb);
    k_out <<<dim3(NB * TT * HH), dim3(256), 0, stream>>>(vclb, qn, wh2, out);
}

// Round 12
// 113.476 us; speedup vs baseline: 1.0905x; 1.0905x over previous
//
#include <hip/hip_runtime.h>
#include <hip/hip_bf16.h>

constexpr int NB   = 2;
constexpr int CIN  = 128;
constexpr int TT   = 8;
constexpr int HH   = 56;
constexpr int WW   = 56;
constexpr int S    = TT * HH * WW;      // 25088
constexpr int DK   = 16;
constexpr int DV   = 128;
constexpr int TAPS = 147;               // 3*7*7
constexpr int NOUT = DK + DV;           // 144
// bf16 channel-first padded v: [b][c:128][t:10][h:62][w:64]
constexpr int VPT = 10, VPH = 62, VPWA = 64;
constexpr int PLANE_A = VPT * VPH * VPWA;     // 39680 bf16 per channel
constexpr int WROW = 22;                // wext row length (taps at 8..15, zero guard)
constexpr int WSTRIDE = 21 * WROW;      // 462 shorts per w
constexpr float EPSf = 1e-6f;

typedef short bf16x8 __attribute__((ext_vector_type(8)));
typedef float f32x4  __attribute__((ext_vector_type(4)));

static __device__ __forceinline__ short f2bf(float f) {
    __hip_bfloat16 h = __float2bfloat16(f);   // RNE
    short s;
    __builtin_memcpy(&s, &h, 2);
    return s;
}

// ---------------------------------------------------------------------------
// k_twp: pack W_proj into MFMA A-fragment order (bf16).  (unchanged)
// ---------------------------------------------------------------------------
__global__ __launch_bounds__(256) void k_twp(
    const float* __restrict__ Wp, short* __restrict__ Wpfrag)
{
    int gid = blockIdx.x * 256 + threadIdx.x;   // < 9*4*64 = 2304
    if (gid >= 9 * 4 * 64) return;
    int lane = gid & 63;
    int kb   = (gid >> 6) & 3;
    int mt   = gid >> 8;
    int n = mt * 16 + (lane & 15);
    int c0 = kb * 32 + (lane >> 4) * 8;
#pragma unroll
    for (int j = 0; j < 8; ++j)
        Wpfrag[(size_t)gid * 8 + j] = f2bf(Wp[n * CIN + c0 + j]);
}

// ---------------------------------------------------------------------------
// k_proj (MFMA, swapped roles): unchanged from R10/R11.
// ---------------------------------------------------------------------------
__global__ __launch_bounds__(256) void k_proj(
    const float* __restrict__ x, const short* __restrict__ Wpfrag,
    float* __restrict__ qn, short* __restrict__ vclb)
{
    int tid  = threadIdx.x;
    int lane = tid & 63;
    int wv   = tid >> 6;
    int bid  = blockIdx.x;                 // < NB * S/128 = 392
    int b    = bid / (S / 128);
    int pbas = (bid - b * (S / 128)) * 128 + wv * 32;

    const float* xb = x + (size_t)b * CIN * S;
    int col = lane & 15;
    int g   = lane >> 4;

    bf16x8 bx[2][4];
#pragma unroll
    for (int n2 = 0; n2 < 2; ++n2) {
        int p = pbas + n2 * 16 + col;
#pragma unroll
        for (int kb = 0; kb < 4; ++kb) {
            const float* xs = xb + (size_t)(kb * 32 + g * 8) * S + p;
#pragma unroll
            for (int j = 0; j < 8; ++j)
                bx[n2][kb][j] = f2bf(xs[(size_t)j * S]);
        }
    }

    f32x4 acc[9][2];
#pragma unroll
    for (int mt = 0; mt < 9; ++mt) {
        acc[mt][0] = {0.f, 0.f, 0.f, 0.f};
        acc[mt][1] = {0.f, 0.f, 0.f, 0.f};
    }

    const bf16x8* wf = reinterpret_cast<const bf16x8*>(Wpfrag);
#pragma unroll
    for (int mt = 0; mt < 9; ++mt) {
#pragma unroll
        for (int kb = 0; kb < 4; ++kb) {
            bf16x8 aw = wf[(mt * 4 + kb) * 64 + lane];
            acc[mt][0] = __builtin_amdgcn_mfma_f32_16x16x32_bf16(
                aw, bx[0][kb], acc[mt][0], 0, 0, 0);
            acc[mt][1] = __builtin_amdgcn_mfma_f32_16x16x32_bf16(
                aw, bx[1][kb], acc[mt][1], 0, 0, 0);
        }
    }

#pragma unroll
    for (int n2 = 0; n2 < 2; ++n2) {
        float ssq = 0.f, ssv = 0.f;
#pragma unroll
        for (int r = 0; r < 4; ++r) ssq += acc[0][n2][r] * acc[0][n2][r];
#pragma unroll
        for (int mt = 1; mt < 9; ++mt)
#pragma unroll
            for (int r = 0; r < 4; ++r) ssv += acc[mt][n2][r] * acc[mt][n2][r];
        ssq += __shfl_xor(ssq, 16, 64);
        ssq += __shfl_xor(ssq, 32, 64);
        ssv += __shfl_xor(ssv, 16, 64);
        ssv += __shfl_xor(ssv, 32, 64);
        float qsc = 1.0f / sqrtf(ssq + EPSf);
        float vsc = 1.0f / sqrtf(ssv + EPSf);

        int p = pbas + n2 * 16 + col;
#pragma unroll
        for (int r = 0; r < 4; ++r)
            qn[((size_t)b * DK + (4 * g + r)) * S + p] = acc[0][n2][r] * qsc;

        int t  = p / (HH * WW);
        int hw = p - t * (HH * WW);
        int h  = hw / WW;
        int w  = hw - h * WW;
        size_t pp = (size_t)(t + 1) * (VPH * VPWA) + (size_t)(h + 3) * VPWA + (w + 3);
        short* vb = vclb + (size_t)b * 128 * PLANE_A + pp;
#pragma unroll
        for (int mt = 1; mt < 9; ++mt)
#pragma unroll
            for (int r = 0; r < 4; ++r) {
                int c = (mt - 1) * 16 + 4 * g + r;
                vb[(size_t)c * PLANE_A] = f2bf(acc[mt][n2][r] * vsc);
            }
    }
}

// ---------------------------------------------------------------------------
// k_out (banded MFMA v3, barrier-free main loop):
//   Phase 1 (2 barriers total): q_s; zero wext; taps wext[w][row][d+8+(w&1)].
//   Main loop (21 rows, NO barriers): B-frags read directly from wext as
//   shifted windows (loop-invariant even byte offsets, 4x ds_read_b32 each;
//   no-overlap lanes read the zero guard); A-frags from global; 10 MFMA/row.
// ---------------------------------------------------------------------------
__global__ __launch_bounds__(256) void k_out(
    const short* __restrict__ vclb, const float* __restrict__ qn,
    const float* __restrict__ wh2, float* __restrict__ out)
{
    __shared__ float q_s[DK * WW];          // 3,584 B
    __shared__ short wext[56 * WSTRIDE];    // 51,744 B

    int tid  = threadIdx.x;
    int lane = tid & 63;
    int wv   = tid >> 6;
    // XCD-chunked swizzle: 896 = 8 * 112
    int bid = blockIdx.x;
    int nid = (bid & 7) * 112 + (bid >> 3);
    int b   = nid / 448;
    int rem = nid - b * 448;
    int t   = rem / 56, h = rem - t * 56;
    int pbase = t * (HH * WW) + h * WW;

    // ---- Phase 1a: stage q row + zero wext
    for (int i = tid; i < DK * WW; i += 256) {
        int k = i / 56, w = i - k * 56;
        q_s[i] = qn[((size_t)b * DK + k) * S + pbase + w];
    }
    {
        int* wz = reinterpret_cast<int*>(wext);
        for (int i = tid; i < 56 * WSTRIDE / 2; i += 256) wz[i] = 0;
    }
    __syncthreads();

    // ---- Phase 1b: taps.  wext[w][row][d + 8 + (w&1)] = weff[w][row,d]
    for (int e = tid; e < 56 * TAPS; e += 256) {
        int w = e / TAPS, r = e - w * TAPS;      // r = row*7 + d
        float a = 0.f;
#pragma unroll
        for (int k = 0; k < DK; ++k)
            a = fmaf(q_s[k * 56 + w], wh2[k * TAPS + r], a);
        int row = r / 7, d = r - row * 7;
        wext[w * WSTRIDE + row * WROW + d + 8 + (w & 1)] = f2bf(a);
    }
    __syncthreads();

    int col = lane & 15, g = lane >> 4;
    int cbase = wv * 32;

    // loop-invariant B-read byte offsets for the 5 active (n,kb) pairs
    // pair p: (n,kb) in {(0,0),(1,0),(1,1),(2,1),(3,1)}
    int boff[5];
    {
        const int NN[5] = {0, 1, 1, 2, 3};
        const int KB[5] = {0, 0, 1, 1, 1};
#pragma unroll
        for (int p = 0; p < 5; ++p) {
            int wl = NN[p] * 16 + col;
            if (wl > 55) wl = 55;                 // ghost columns (discarded)
            int base = KB[p] * 32 + g * 8 - wl;   // window start in d-space
            bool ov = (base >= -7) && (base <= 6);
            int r0 = ov ? (base + 8 + (wl & 1)) : 0;   // provably even
            boff[p] = (wl * WSTRIDE + r0) * 2;         // bytes
        }
    }

    const short* vb0 = vclb + (size_t)b * 128 * PLANE_A
                     + (size_t)(cbase + col) * PLANE_A + g * 8;
    const short* vb1 = vb0 + (size_t)16 * PLANE_A;

    f32x4 acc[2][4];
#pragma unroll
    for (int m2 = 0; m2 < 2; ++m2)
#pragma unroll
        for (int n = 0; n < 4; ++n) acc[m2][n] = {0.f, 0.f, 0.f, 0.f};

    const char* wbase = reinterpret_cast<const char*>(wext);

#pragma unroll 3
    for (int r = 0; r < 21; ++r) {
        int dz = r / 7, dy = r - dz * 7;
        size_t o = (size_t)(t + dz) * (VPH * VPWA) + (size_t)(h + dy) * VPWA;

        bf16x8 a00 = *reinterpret_cast<const bf16x8*>(vb0 + o);
        bf16x8 a01 = *reinterpret_cast<const bf16x8*>(vb0 + o + 32);
        bf16x8 a10 = *reinterpret_cast<const bf16x8*>(vb1 + o);
        bf16x8 a11 = *reinterpret_cast<const bf16x8*>(vb1 + o + 32);

        int rb = r * (WROW * 2);
        bf16x8 bb[5];
#pragma unroll
        for (int p = 0; p < 5; ++p) {
            const int* wp = reinterpret_cast<const int*>(wbase + boff[p] + rb);
            int tmp[4] = {wp[0], wp[1], wp[2], wp[3]};
            __builtin_memcpy(&bb[p], tmp, 16);
        }

        acc[0][0] = __builtin_amdgcn_mfma_f32_16x16x32_bf16(a00, bb[0], acc[0][0], 0, 0, 0);
        acc[0][1] = __builtin_amdgcn_mfma_f32_16x16x32_bf16(a00, bb[1], acc[0][1], 0, 0, 0);
        acc[0][1] = __builtin_amdgcn_mfma_f32_16x16x32_bf16(a01, bb[2], acc[0][1], 0, 0, 0);
        acc[0][2] = __builtin_amdgcn_mfma_f32_16x16x32_bf16(a01, bb[3], acc[0][2], 0, 0, 0);
        acc[0][3] = __builtin_amdgcn_mfma_f32_16x16x32_bf16(a01, bb[4], acc[0][3], 0, 0, 0);
        acc[1][0] = __builtin_amdgcn_mfma_f32_16x16x32_bf16(a10, bb[0], acc[1][0], 0, 0, 0);
        acc[1][1] = __builtin_amdgcn_mfma_f32_16x16x32_bf16(a10, bb[1], acc[1][1], 0, 0, 0);
        acc[1][1] = __builtin_amdgcn_mfma_f32_16x16x32_bf16(a11, bb[2], acc[1][1], 0, 0, 0);
        acc[1][2] = __builtin_amdgcn_mfma_f32_16x16x32_bf16(a11, bb[3], acc[1][2], 0, 0, 0);
        acc[1][3] = __builtin_amdgcn_mfma_f32_16x16x32_bf16(a11, bb[4], acc[1][3], 0, 0, 0);
    }

    // ---- epilogue: D[m=c][n=w], c = cbase + m2*16 + 4g + rr, w = n*16 + col
#pragma unroll
    for (int m2 = 0; m2 < 2; ++m2) {
#pragma unroll
        for (int n = 0; n < 4; ++n) {
            int w = n * 16 + col;
            if (w < 56) {
                size_t ob = ((size_t)b * DV + cbase + m2 * 16 + 4 * g) * S + pbase + w;
#pragma unroll
                for (int rr = 0; rr < 4; ++rr)
                    out[ob + (size_t)rr * S] = acc[m2][n][rr];
            }
        }
    }
}

// ---------------------------------------------------------------------------
extern "C" void kernel_launch(void* const* d_in, const int* in_sizes, int n_in,
                              void* d_out, int out_size, void* d_ws, size_t ws_size,
                              hipStream_t stream)
{
    const float* x   = (const float*)d_in[0];   // (2,128,8,56,56)
    const float* Wp  = (const float*)d_in[1];   // (144,128)
    const float* wh2 = (const float*)d_in[2];   // (16,1,3,7,7) -> [k][147]
    float* out = (float*)d_out;                 // (2,128,8,56,56)

    float* ws     = (float*)d_ws;
    short* Wpfrag = (short*)ws;                        // 18,432 shorts
    float* qn     = ws + 9216;                         // NB*DK*S fp32
    short* vclb   = (short*)(qn + (size_t)NB * DK * S);// NB*128*PLANE_A bf16

    size_t vclb_bytes = (size_t)NB * 128 * PLANE_A * sizeof(short);  // 20.3 MB

    k_twp <<<dim3(9), dim3(256), 0, stream>>>(Wp, Wpfrag);
    hipMemsetAsync(vclb, 0, vclb_bytes, stream);
    k_proj<<<dim3(NB * S / 128), dim3(256), 0, stream>>>(x, Wpfrag, qn, vclb);
    k_out <<<dim3(NB * TT * HH), dim3(256), 0, stream>>>(vclb, qn, wh2, out);
}